// Round 3
// baseline (411.807 us; speedup 1.0000x reference)
//
#include <hip/hip_runtime.h>
#include <hip/hip_bf16.h>

#define HWsz 16384
#define Cdim 64
#define HIDd 128
#define NEXP 4
#define NBAT 16

typedef _Float16 h8 __attribute__((ext_vector_type(8)));
typedef _Float16 h4 __attribute__((ext_vector_type(4)));
typedef float f4 __attribute__((ext_vector_type(4)));

// d_ws layout (bytes)
#define OFF_W1F 0        // 4*128*64 f16   = 65536 B
#define OFF_W2F 65536    // 4*128*128 f16  = 131072 B
#define OFF_W3F 196608   // 4*64*128 f16   = 65536 B
#define OFF_B1F 262144   // 4*128 f32      = 2048 B
#define OFF_B2F 264192   // 4*128 f32      = 2048 B
#define OFF_B3F 266240   // 4*64 f32       = 1024 B
#define OFF_GAP 267264   // 16*64 f32      = 4096 B

// ---------------- prep: BN fold + f16 cast + global average pool ----------------
// blocks 0..1023: gap (bc = blockIdx.x); blocks 1024..1540: fold.
__global__ void prep_k(const float* __restrict__ x,
                       const float* __restrict__ W1, const float* __restrict__ b1,
                       const float* __restrict__ g1, const float* __restrict__ be1,
                       const float* __restrict__ m1, const float* __restrict__ v1,
                       const float* __restrict__ W2, const float* __restrict__ b2,
                       const float* __restrict__ g2, const float* __restrict__ be2,
                       const float* __restrict__ m2, const float* __restrict__ v2,
                       const float* __restrict__ W3, const float* __restrict__ b3,
                       _Float16* __restrict__ W1f, _Float16* __restrict__ W2f,
                       _Float16* __restrict__ W3f,
                       float* __restrict__ b1f, float* __restrict__ b2f,
                       float* __restrict__ b3f, float* __restrict__ gap)
{
  const int t = threadIdx.x;
  if (blockIdx.x < 1024) {
    const int bc = blockIdx.x;           // b*64 + c
    const float* p = x + (size_t)bc * HWsz;
    float s = 0.f;
    for (int i = t; i < HWsz / 4; i += 256) {
      const float4 v = ((const float4*)p)[i];
      s += v.x + v.y + v.z + v.w;
    }
    for (int off = 32; off; off >>= 1) s += __shfl_down(s, off, 64);
    __shared__ float red[4];
    if ((t & 63) == 0) red[t >> 6] = s;
    __syncthreads();
    if (t == 0) gap[bc] = (red[0] + red[1] + red[2] + red[3]) * (1.0f / HWsz);
    return;
  }
  const int i = (blockIdx.x - 1024) * 256 + t;
  if (i < 32768) {                       // W1 [e][o][c], eo = i/64
    const int eo = i >> 6;
    const float inv = g1[eo] * rsqrtf(v1[eo] + 1e-5f);
    W1f[i] = (_Float16)(W1[i] * inv);
  } else if (i < 98304) {                // W2 [e][o][i], eo = j/128
    const int j = i - 32768;
    const int eo = j >> 7;
    const float inv = g2[eo] * rsqrtf(v2[eo] + 1e-5f);
    W2f[j] = (_Float16)(W2[j] * inv);
  } else if (i < 131072) {               // W3 (no BN)
    const int k = i - 98304;
    W3f[k] = (_Float16)W3[k];
  } else if (i < 131584) {               // b1'
    const int l = i - 131072;
    const float inv = g1[l] * rsqrtf(v1[l] + 1e-5f);
    b1f[l] = b1[l] * inv + be1[l] - m1[l] * inv;
  } else if (i < 132096) {               // b2'
    const int l = i - 131584;
    const float inv = g2[l] * rsqrtf(v2[l] + 1e-5f);
    b2f[l] = b2[l] * inv + be2[l] - m2[l] * inv;
  } else if (i < 132352) {               // b3'
    b3f[i - 132096] = b3[i - 132096];
  }
}

// ---------------- fused top-2 expert MLP, barrier-free ----------------
// grid (256, 16): blockIdx.x = 64-wide position tile, blockIdx.y = sample b.
// Each of the 4 waves owns 16 positions and computes ALL channels for them,
// so layer chaining needs only wave-private LDS scratch (no __syncthreads).
__global__ __launch_bounds__(256, 4)
void moe_main_k(const float* __restrict__ x, float* __restrict__ out,
                float* __restrict__ aux,
                const _Float16* __restrict__ W1f, const _Float16* __restrict__ W2f,
                const _Float16* __restrict__ W3f,
                const float* __restrict__ b1f, const float* __restrict__ b2f,
                const float* __restrict__ b3f,
                const float* __restrict__ gapp, const float* __restrict__ gwt,
                const float* __restrict__ gb)
{
  // per-wave private scratch: [buf][wave][n=16][k=128 + pad 8]
  // row stride 272 B -> b128 reads hit banks 4*(ln+q)%32: uniform, conflict-free
  __shared__ __align__(16) _Float16 Hs[2][4][16][136];

  const int b  = blockIdx.y;
  const int n0 = blockIdx.x << 6;
  const int t  = threadIdx.x;
  const int w  = t >> 6;
  const int lane = t & 63;
  const int ln = lane & 15;   // MFMA m/n lane index
  const int q  = lane >> 4;   // quad

  _Float16 (*h1)[136] = Hs[0][w];
  _Float16 (*h2)[136] = Hs[1][w];

  // ---- X B-fragments straight from global: lane needs x[b][c][n], c=ks*32+q*8+j
  const float* xb = x + (size_t)b * (Cdim * HWsz) + n0 + (w << 4) + ln;
  h8 xf[2];
#pragma unroll
  for (int ks = 0; ks < 2; ks++)
#pragma unroll
    for (int j = 0; j < 8; j++)
      xf[ks][j] = (_Float16)xb[(size_t)(ks * 32 + (q << 3) + j) * HWsz];

  // ---- gate (every wave computes; result is wave-uniform)
  int e0u, e1u; float w0u, w1u;
  {
    const int eg = lane >> 4, cg = (lane & 15) << 2;
    float part = 0.f;
#pragma unroll
    for (int c = 0; c < 4; c++)
      part += gapp[b * Cdim + cg + c] * gwt[eg * Cdim + cg + c];
    part += __shfl_xor(part, 1, 64);
    part += __shfl_xor(part, 2, 64);
    part += __shfl_xor(part, 4, 64);
    part += __shfl_xor(part, 8, 64);
    float p[4];
#pragma unroll
    for (int e = 0; e < 4; e++) p[e] = __shfl(part, e * 16, 64) + gb[e];
    const float mx = fmaxf(fmaxf(p[0], p[1]), fmaxf(p[2], p[3]));
    float sum = 0.f;
#pragma unroll
    for (int e = 0; e < 4; e++) { p[e] = expf(p[e] - mx); sum += p[e]; }
    const float inv = 1.f / sum;
#pragma unroll
    for (int e = 0; e < 4; e++) p[e] *= inv;
    int i0 = 0;
#pragma unroll
    for (int e = 1; e < 4; e++) if (p[e] > p[i0]) i0 = e;
    int i1 = (i0 == 0) ? 1 : 0;
#pragma unroll
    for (int e = 0; e < 4; e++) if (e != i0 && p[e] > p[i1]) i1 = e;
    const float s2 = p[i0] + p[i1] + 1e-8f;
    e0u = __builtin_amdgcn_readfirstlane(i0);
    e1u = __builtin_amdgcn_readfirstlane(i1);
    w0u = __uint_as_float(__builtin_amdgcn_readfirstlane(__float_as_uint(p[i0] / s2)));
    w1u = __uint_as_float(__builtin_amdgcn_readfirstlane(__float_as_uint(p[i1] / s2)));
  }

  // ---- aux loss: one wave of one block. ALL cross-lane ops in full-wave
  // context (shfl from an exec-masked-off lane returns 0 on CDNA — R2 bug).
  if (blockIdx.x == 0 && blockIdx.y == 0 && t < 64) {
    const int ab = lane >> 2, ae = lane & 3;
    float lg = gb[ae];
    for (int c = 0; c < Cdim; c++) lg += gapp[ab * Cdim + c] * gwt[ae * Cdim + c];
    float m2 = fmaxf(lg, __shfl_xor(lg, 1, 64));
    m2 = fmaxf(m2, __shfl_xor(m2, 2, 64));
    const float ex = expf(lg - m2);
    float sm = ex + __shfl_xor(ex, 1, 64);
    sm = sm + __shfl_xor(sm, 2, 64);
    const float pp = ex / sm;
    const int base = lane & ~3;
    float qa[4];
#pragma unroll
    for (int e = 0; e < 4; e++) qa[e] = __shfl(pp, base + e, 64);
    int j0 = 0;
#pragma unroll
    for (int e = 1; e < 4; e++) if (qa[e] > qa[j0]) j0 = e;
    int j1 = (j0 == 0) ? 1 : 0;
#pragma unroll
    for (int e = 0; e < 4; e++) if (e != j0 && qa[e] > qa[j1]) j1 = e;
    const float ss = qa[j0] + qa[j1] + 1e-8f;
    float imp = (ae == j0 || ae == j1) ? pp / ss : 0.f;
    imp += __shfl_xor(imp, 4, 64);
    imp += __shfl_xor(imp, 8, 64);
    imp += __shfl_xor(imp, 16, 64);
    imp += __shfl_xor(imp, 32, 64);
    // every lane now holds the usage total for its expert ae
    float tot = imp + __shfl_xor(imp, 1, 64);
    tot += __shfl_xor(tot, 2, 64);                 // sum over 4 experts
    const float mean = tot * 0.25f;
    const float d = imp - mean;
    float var4 = d * d + __shfl_xor(d * d, 1, 64);
    var4 += __shfl_xor(var4, 2, 64);
    const float var = var4 * 0.25f;
    if (lane == 0) aux[0] = var / (mean * mean + 1e-10f);
  }

  f4 oacc[4];
#pragma unroll
  for (int i = 0; i < 4; i++) oacc[i] = f4{0.f, 0.f, 0.f, 0.f};

#pragma unroll
  for (int slot = 0; slot < 2; slot++) {
    const int   e  = slot ? e1u : e0u;
    const float we = slot ? w1u : w0u;
    const _Float16* w1p = W1f + e * (HIDd * Cdim);
    const _Float16* w2p = W2f + e * (HIDd * HIDd);
    const _Float16* w3p = W3f + e * (Cdim * HIDd);
    const float* bb1 = b1f + e * HIDd;
    const float* bb2 = b2f + e * HIDd;
    const float* bb3 = b3f + e * Cdim;

    // ---- Layer 1: h1[n][o] = relu(W1' X + b1'), M=128, K=64, n=16
#pragma unroll
    for (int mi = 0; mi < 8; mi++) {
      const _Float16* wp = w1p + ((mi << 4) + ln) * Cdim;
      const h8 a0 = *(const h8*)(wp + (q << 3));
      const h8 a1 = *(const h8*)(wp + 32 + (q << 3));
      f4 acc = {0.f, 0.f, 0.f, 0.f};
      acc = __builtin_amdgcn_mfma_f32_16x16x32_f16(a0, xf[0], acc, 0, 0, 0);
      acc = __builtin_amdgcn_mfma_f32_16x16x32_f16(a1, xf[1], acc, 0, 0, 0);
      const f4 bias = *(const f4*)(bb1 + (mi << 4) + (q << 2));
      h4 hv;
#pragma unroll
      for (int r = 0; r < 4; r++) hv[r] = (_Float16)fmaxf(acc[r] + bias[r], 0.f);
      *(h4*)&h1[ln][(mi << 4) + (q << 2)] = hv;
    }

    // ---- Layer 2: h2 = relu(W2' h1 + b2'), M=128, K=128
    h8 bf[4];
#pragma unroll
    for (int ks = 0; ks < 4; ks++) bf[ks] = *(const h8*)&h1[ln][(ks << 5) + (q << 3)];
#pragma unroll
    for (int mi = 0; mi < 8; mi++) {
      const _Float16* wp = w2p + ((mi << 4) + ln) * HIDd;
      f4 acc = {0.f, 0.f, 0.f, 0.f};
#pragma unroll
      for (int ks = 0; ks < 4; ks++) {
        const h8 a = *(const h8*)(wp + (ks << 5) + (q << 3));
        acc = __builtin_amdgcn_mfma_f32_16x16x32_f16(a, bf[ks], acc, 0, 0, 0);
      }
      const f4 bias = *(const f4*)(bb2 + (mi << 4) + (q << 2));
      h4 hv;
#pragma unroll
      for (int r = 0; r < 4; r++) hv[r] = (_Float16)fmaxf(acc[r] + bias[r], 0.f);
      *(h4*)&h2[ln][(mi << 4) + (q << 2)] = hv;
    }

    // ---- Layer 3: oacc += we * (W3 h2 + b3), M=64, K=128
    h8 cf[4];
#pragma unroll
    for (int ks = 0; ks < 4; ks++) cf[ks] = *(const h8*)&h2[ln][(ks << 5) + (q << 3)];
#pragma unroll
    for (int mi = 0; mi < 4; mi++) {
      const _Float16* wp = w3p + ((mi << 4) + ln) * HIDd;
      f4 acc = {0.f, 0.f, 0.f, 0.f};
#pragma unroll
      for (int ks = 0; ks < 4; ks++) {
        const h8 a = *(const h8*)(wp + (ks << 5) + (q << 3));
        acc = __builtin_amdgcn_mfma_f32_16x16x32_f16(a, cf[ks], acc, 0, 0, 0);
      }
      const f4 bias = *(const f4*)(bb3 + (mi << 4) + (q << 2));
#pragma unroll
      for (int r = 0; r < 4; r++) oacc[mi][r] += we * (acc[r] + bias[r]);
    }
  }

  // ---- store output (fp32): lane(ln,q) -> c = mi*16+q*4+r, n = n0+w*16+ln
  float* ob = out + (size_t)b * (Cdim * HWsz) + n0 + (w << 4) + ln;
#pragma unroll
  for (int mi = 0; mi < 4; mi++)
#pragma unroll
    for (int r = 0; r < 4; r++)
      ob[(size_t)((mi << 4) + (q << 2) + r) * HWsz] = oacc[mi][r];
}

extern "C" void kernel_launch(void* const* d_in, const int* in_sizes, int n_in,
                              void* d_out, int out_size, void* d_ws, size_t ws_size,
                              hipStream_t stream)
{
  const float* x   = (const float*)d_in[0];
  const float* W1  = (const float*)d_in[1];
  const float* b1  = (const float*)d_in[2];
  const float* g1  = (const float*)d_in[3];
  const float* be1 = (const float*)d_in[4];
  const float* m1  = (const float*)d_in[5];
  const float* v1  = (const float*)d_in[6];
  const float* W2  = (const float*)d_in[7];
  const float* b2  = (const float*)d_in[8];
  const float* g2  = (const float*)d_in[9];
  const float* be2 = (const float*)d_in[10];
  const float* m2  = (const float*)d_in[11];
  const float* v2  = (const float*)d_in[12];
  const float* W3  = (const float*)d_in[13];
  const float* b3  = (const float*)d_in[14];
  const float* gwt = (const float*)d_in[15];
  const float* gb  = (const float*)d_in[16];

  char* ws = (char*)d_ws;
  _Float16* W1f = (_Float16*)(ws + OFF_W1F);
  _Float16* W2f = (_Float16*)(ws + OFF_W2F);
  _Float16* W3f = (_Float16*)(ws + OFF_W3F);
  float* b1f = (float*)(ws + OFF_B1F);
  float* b2f = (float*)(ws + OFF_B2F);
  float* b3f = (float*)(ws + OFF_B3F);
  float* gap = (float*)(ws + OFF_GAP);

  float* out = (float*)d_out;
  float* aux = out + (size_t)NBAT * Cdim * HWsz;  // d_out[16777216]

  hipLaunchKernelGGL(prep_k, dim3(1541), dim3(256), 0, stream,
                     x, W1, b1, g1, be1, m1, v1, W2, b2, g2, be2, m2, v2, W3, b3,
                     W1f, W2f, W3f, b1f, b2f, b3f, gap);
  hipLaunchKernelGGL(moe_main_k, dim3(HWsz / 64, NBAT), dim3(256), 0, stream,
                     x, out, aux, W1f, W2f, W3f, b1f, b2f, b3f, gap, gwt, gb);
}